// Round 1
// 493.988 us; speedup vs baseline: 1.0250x; 1.0250x over previous
//
#include <hip/hip_runtime.h>
#include <math.h>

#define BB 16
#define CC 64
#define HH 256
#define WW 256
#define HWSZ (HH * WW)
#define NP (BB * CC)   // 1024 planes
#define STRIPS 4       // strips per plane (conv); wave owns HH/(STRIPS*4)=16 rows
#define RPW (HH / (STRIPS * 4))

typedef float f4 __attribute__((ext_vector_type(4)));

// ---------------- Kernel 1: per-plane mean ----------------
__global__ __launch_bounds__(256) void mean_kernel(const float* __restrict__ x,
                                                   float* __restrict__ avg) {
    int p = blockIdx.x;
    const float4* xp = (const float4*)(x + (size_t)p * HWSZ);
    float s0 = 0.f, s1 = 0.f, s2 = 0.f, s3 = 0.f;
    for (int i = threadIdx.x; i < HWSZ / 4; i += 1024) {
        float4 a = xp[i];
        float4 b = xp[i + 256];
        float4 c = xp[i + 512];
        float4 d = xp[i + 768];
        s0 += a.x + a.y + a.z + a.w;
        s1 += b.x + b.y + b.z + b.w;
        s2 += c.x + c.y + c.z + c.w;
        s3 += d.x + d.y + d.z + d.w;
    }
    float s = (s0 + s1) + (s2 + s3);
    for (int off = 32; off > 0; off >>= 1) s += __shfl_down(s, off, 64);
    __shared__ float ws[4];
    int lane = threadIdx.x & 63, wid = threadIdx.x >> 6;
    if (lane == 0) ws[wid] = s;
    __syncthreads();
    if (threadIdx.x == 0) {
        avg[p] = (ws[0] + ws[1] + ws[2] + ws[3]) * (1.0f / (float)HWSZ);
    }
}

// ---------------- Kernel 2: dyn = avg @ w1.T + b1, sigmoid ----------------
__global__ __launch_bounds__(256) void wk_kernel(const float* __restrict__ avg,
                                                 const float* __restrict__ w1,
                                                 const float* __restrict__ b1,
                                                 float* __restrict__ wk) {
    int idx = blockIdx.x * 256 + threadIdx.x;
    if (idx >= BB * CC * 9) return;
    int b = idx / (CC * 9);
    int j = idx % (CC * 9);
    const float* a = avg + b * CC;
    const float* wrow = w1 + (size_t)j * CC;
    float s = b1[j];
#pragma unroll
    for (int c2 = 0; c2 < CC; ++c2) s += a[c2] * wrow[c2];
    wk[idx] = 1.0f / (1.0f + expf(-s));
}

// ---------------- Kernel 3: depthwise 3x3 conv + fused epilogue ----------------
// v2: 4-way strip split per plane (grid NP*STRIPS, 256 thr) -> 32 waves/CU
// resident (2x MLP vs v1's 16), each wave owns 16 rows. Output stores are
// nontemporal so x (268 MB, ~95% resident in the 256 MB Infinity Cache after
// mean_kernel) is not evicted by output write-allocate -> conv x-reads stay
// L3 hits. Halo cost: 2 extra row-loads per 16-row strip = +12.5% read.
__global__ __launch_bounds__(256, 8) void conv_kernel(const float* __restrict__ x,
                                                      const float* __restrict__ wk,
                                                      const float* __restrict__ fscale,
                                                      const float* __restrict__ conv_bias,
                                                      float* __restrict__ out) {
    const int p     = blockIdx.x >> 2;            // plane
    const int strip = blockIdx.x & (STRIPS - 1);  // strip within plane
    const int wave = threadIdx.x >> 6;
    const int lane = threadIdx.x & 63;
    const int c = p & (CC - 1);
    const int h0 = strip * (HH / STRIPS) + wave * RPW;
    const float* xp = x + (size_t)p * HWSZ;
    float* op = out + (size_t)p * HWSZ;

    const float* wkp = wk + p * 9;
    float k0 = wkp[0], k1 = wkp[1], k2 = wkp[2];
    float k3 = wkp[3], k4 = wkp[4], k5 = wkp[5];
    float k6 = wkp[6], k7 = wkp[7], k8 = wkp[8];
    const float fs = fscale[c];
    const float cb = conv_bias[c];

    auto ldrow = [&](int r) -> f4 {
        if ((unsigned)r < (unsigned)HH) return ((const f4*)(xp + r * WW))[lane];
        return (f4){0.f, 0.f, 0.f, 0.f};
    };
    auto haloL = [&](float w) { float v = __shfl_up(w, 1, 64); return lane == 0 ? 0.f : v; };
    auto haloR = [&](float v0) { float v = __shfl_down(v0, 1, 64); return lane == 63 ? 0.f : v; };

    f4 rp = ldrow(h0 - 1);   // row h-1
    f4 rc = ldrow(h0);       // row h
    f4 rn = ldrow(h0 + 1);   // row h+1
    float lp = haloL(rp.w), Rp = haloR(rp.x);
    float lc = haloL(rc.w), Rc = haloR(rc.x);

    for (int h = h0; h < h0 + RPW; ++h) {
        f4 rn2 = ldrow(h + 2);           // prefetch: consumed next iter
        float ln = haloL(rn.w), Rn = haloR(rn.x);

        f4 y;
        y.x = cb + k0 * lp   + k1 * rp.x + k2 * rp.y
                 + k3 * lc   + k4 * rc.x + k5 * rc.y
                 + k6 * ln   + k7 * rn.x + k8 * rn.y;
        y.y = cb + k0 * rp.x + k1 * rp.y + k2 * rp.z
                 + k3 * rc.x + k4 * rc.y + k5 * rc.z
                 + k6 * rn.x + k7 * rn.y + k8 * rn.z;
        y.z = cb + k0 * rp.y + k1 * rp.z + k2 * rp.w
                 + k3 * rc.y + k4 * rc.z + k5 * rc.w
                 + k6 * rn.y + k7 * rn.z + k8 * rn.w;
        y.w = cb + k0 * rp.z + k1 * rp.w + k2 * Rp
                 + k3 * rc.z + k4 * rc.w + k5 * Rc
                 + k6 * rn.z + k7 * rn.w + k8 * Rn;

        f4 o;
        o.x = (rc.x - y.x) * fs * rc.x + y.x;
        o.y = (rc.y - y.y) * fs * rc.y + y.y;
        o.z = (rc.z - y.z) * fs * rc.z + y.z;
        o.w = (rc.w - y.w) * fs * rc.w + y.w;
        __builtin_nontemporal_store(o, (f4*)(op + h * WW) + lane);

        rp = rc; rc = rn; rn = rn2;
        lp = lc; Rp = Rc;
        lc = ln; Rc = Rn;
    }
}

extern "C" void kernel_launch(void* const* d_in, const int* in_sizes, int n_in,
                              void* d_out, int out_size, void* d_ws, size_t ws_size,
                              hipStream_t stream) {
    const float* x         = (const float*)d_in[0];
    const float* w1        = (const float*)d_in[1];
    const float* b1        = (const float*)d_in[2];
    const float* fscale    = (const float*)d_in[3];
    const float* conv_bias = (const float*)d_in[4];
    float* out = (float*)d_out;

    float* avg = (float*)d_ws;        // 1024 floats
    float* wk  = avg + NP;            // 9216 floats

    mean_kernel<<<NP, 256, 0, stream>>>(x, avg);
    wk_kernel<<<(BB * CC * 9 + 255) / 256, 256, 0, stream>>>(avg, w1, b1, wk);
    conv_kernel<<<NP * STRIPS, 256, 0, stream>>>(x, wk, fscale, conv_bias, out);
}

// Round 2
// 486.725 us; speedup vs baseline: 1.0403x; 1.0149x over previous
//
#include <hip/hip_runtime.h>
#include <math.h>

#define BB 16
#define CC 64
#define HH 256
#define WW 256
#define HWSZ (HH * WW)
#define NP (BB * CC)   // 1024 planes
#define STRIPS 4       // strips per plane; wave owns 16 rows
#define RPW (HH / (STRIPS * 4))

typedef float f4 __attribute__((ext_vector_type(4)));

// ---------------- Kernel 1: per-plane mean ----------------
__global__ __launch_bounds__(256) void mean_kernel(const float* __restrict__ x,
                                                   float* __restrict__ avg) {
    int p = blockIdx.x;
    const float4* xp = (const float4*)(x + (size_t)p * HWSZ);
    float s0 = 0.f, s1 = 0.f, s2 = 0.f, s3 = 0.f;
    for (int i = threadIdx.x; i < HWSZ / 4; i += 1024) {
        float4 a = xp[i];
        float4 b = xp[i + 256];
        float4 c = xp[i + 512];
        float4 d = xp[i + 768];
        s0 += a.x + a.y + a.z + a.w;
        s1 += b.x + b.y + b.z + b.w;
        s2 += c.x + c.y + c.z + c.w;
        s3 += d.x + d.y + d.z + d.w;
    }
    float s = (s0 + s1) + (s2 + s3);
    for (int off = 32; off > 0; off >>= 1) s += __shfl_down(s, off, 64);
    __shared__ float ws[4];
    int lane = threadIdx.x & 63, wid = threadIdx.x >> 6;
    if (lane == 0) ws[wid] = s;
    __syncthreads();
    if (threadIdx.x == 0) {
        avg[p] = (ws[0] + ws[1] + ws[2] + ws[3]) * (1.0f / (float)HWSZ);
    }
}

// ---------------- Kernel 2: depthwise 3x3 conv + fused MLP + epilogue ----------------
// v3: strip-major block order (resident blocks cover low rows of ALL planes ->
// read order matches L3 LRU age from the mean pass), depth-2 row pipeline
// (2 float4 loads in flight/lane), launch_bounds(256,4) (no spill risk),
// per-block fused tap computation (9 threads x 64-FMA dot + sigmoid).
__global__ __launch_bounds__(256, 4) void conv_kernel(const float* __restrict__ x,
                                                      const float* __restrict__ avg,
                                                      const float* __restrict__ w1,
                                                      const float* __restrict__ b1,
                                                      const float* __restrict__ fscale,
                                                      const float* __restrict__ conv_bias,
                                                      float* __restrict__ out) {
    const int p     = blockIdx.x & (NP - 1);   // plane (strip-major)
    const int strip = blockIdx.x >> 10;        // 0..3
    const int wave  = threadIdx.x >> 6;
    const int lane  = threadIdx.x & 63;
    const int c = p & (CC - 1);
    const int b = p >> 6;
    const int h0 = strip * (HH / STRIPS) + wave * RPW;
    const float* xp = x + (size_t)p * HWSZ;
    float* op = out + (size_t)p * HWSZ;

    // --- fused dynamic-tap computation: dyn[b, c*9+j] = b1 + avg[b,:] . w1[c*9+j,:]
    __shared__ float kk[12];
    if (threadIdx.x < 9) {
        const float* a    = avg + b * CC;
        const float* wrow = w1 + (size_t)(c * 9 + threadIdx.x) * CC;
        float s = b1[c * 9 + threadIdx.x];
#pragma unroll
        for (int c2 = 0; c2 < CC; ++c2) s += a[c2] * wrow[c2];
        kk[threadIdx.x] = 1.0f / (1.0f + expf(-s));
    }
    __syncthreads();
    const float k0 = kk[0], k1 = kk[1], k2 = kk[2];
    const float k3 = kk[3], k4 = kk[4], k5 = kk[5];
    const float k6 = kk[6], k7 = kk[7], k8 = kk[8];
    const float fs = fscale[c];
    const float cb = conv_bias[c];

    auto ldrow = [&](int r) -> f4 {
        if ((unsigned)r < (unsigned)HH) return ((const f4*)(xp + r * WW))[lane];
        return (f4){0.f, 0.f, 0.f, 0.f};
    };
    auto hL = [&](f4 v) { float t = __shfl_up(v.w, 1, 64); return lane == 0 ? 0.f : t; };
    auto hR = [&](f4 v) { float t = __shfl_down(v.x, 1, 64); return lane == 63 ? 0.f : t; };

    // register window: rows h-1, h, h+1, h+2 (rA..rD) + 2 prefetched (rE,rF)
    f4 rA = ldrow(h0 - 1);
    f4 rB = ldrow(h0);
    f4 rC = ldrow(h0 + 1);
    f4 rD = ldrow(h0 + 2);
    float lA = hL(rA), RA = hR(rA);
    float lB = hL(rB), RB = hR(rB);
    float lC = hL(rC), RC = hR(rC);
    float lD = hL(rD), RD = hR(rD);

    for (int h = h0; h < h0 + RPW; h += 2) {
        f4 rE = ldrow(h + 3);   // in flight during compute
        f4 rF = ldrow(h + 4);   // in flight during compute

        // row h: sources rA (h-1), rB (h), rC (h+1)
        f4 y0;
        y0.x = cb + k0 * lA   + k1 * rA.x + k2 * rA.y
                  + k3 * lB   + k4 * rB.x + k5 * rB.y
                  + k6 * lC   + k7 * rC.x + k8 * rC.y;
        y0.y = cb + k0 * rA.x + k1 * rA.y + k2 * rA.z
                  + k3 * rB.x + k4 * rB.y + k5 * rB.z
                  + k6 * rC.x + k7 * rC.y + k8 * rC.z;
        y0.z = cb + k0 * rA.y + k1 * rA.z + k2 * rA.w
                  + k3 * rB.y + k4 * rB.z + k5 * rB.w
                  + k6 * rC.y + k7 * rC.z + k8 * rC.w;
        y0.w = cb + k0 * rA.z + k1 * rA.w + k2 * RA
                  + k3 * rB.z + k4 * rB.w + k5 * RB
                  + k6 * rC.z + k7 * rC.w + k8 * RC;
        f4 o0;
        o0.x = (rB.x - y0.x) * fs * rB.x + y0.x;
        o0.y = (rB.y - y0.y) * fs * rB.y + y0.y;
        o0.z = (rB.z - y0.z) * fs * rB.z + y0.z;
        o0.w = (rB.w - y0.w) * fs * rB.w + y0.w;
        __builtin_nontemporal_store(o0, (f4*)(op + h * WW) + lane);

        // row h+1: sources rB (h), rC (h+1), rD (h+2)
        f4 y1;
        y1.x = cb + k0 * lB   + k1 * rB.x + k2 * rB.y
                  + k3 * lC   + k4 * rC.x + k5 * rC.y
                  + k6 * lD   + k7 * rD.x + k8 * rD.y;
        y1.y = cb + k0 * rB.x + k1 * rB.y + k2 * rB.z
                  + k3 * rC.x + k4 * rC.y + k5 * rC.z
                  + k6 * rD.x + k7 * rD.y + k8 * rD.z;
        y1.z = cb + k0 * rB.y + k1 * rB.z + k2 * rB.w
                  + k3 * rC.y + k4 * rC.z + k5 * rC.w
                  + k6 * rD.y + k7 * rD.z + k8 * rD.w;
        y1.w = cb + k0 * rB.z + k1 * rB.w + k2 * RB
                  + k3 * rC.z + k4 * rC.w + k5 * RC
                  + k6 * rD.z + k7 * rD.w + k8 * RD;
        f4 o1;
        o1.x = (rC.x - y1.x) * fs * rC.x + y1.x;
        o1.y = (rC.y - y1.y) * fs * rC.y + y1.y;
        o1.z = (rC.z - y1.z) * fs * rC.z + y1.z;
        o1.w = (rC.w - y1.w) * fs * rC.w + y1.w;
        __builtin_nontemporal_store(o1, (f4*)(op + (h + 1) * WW) + lane);

        // halos for the prefetched rows (after compute: loads have landed)
        float lE = hL(rE), RE = hR(rE);
        float lF = hL(rF), RF = hR(rF);

        // shift window by 2
        rA = rC; lA = lC; RA = RC;
        rB = rD; lB = lD; RB = RD;
        rC = rE; lC = lE; RC = RE;
        rD = rF; lD = lF; RD = RF;
    }
}

extern "C" void kernel_launch(void* const* d_in, const int* in_sizes, int n_in,
                              void* d_out, int out_size, void* d_ws, size_t ws_size,
                              hipStream_t stream) {
    const float* x         = (const float*)d_in[0];
    const float* w1        = (const float*)d_in[1];
    const float* b1        = (const float*)d_in[2];
    const float* fscale    = (const float*)d_in[3];
    const float* conv_bias = (const float*)d_in[4];
    float* out = (float*)d_out;

    float* avg = (float*)d_ws;        // 1024 floats

    mean_kernel<<<NP, 256, 0, stream>>>(x, avg);
    conv_kernel<<<NP * STRIPS, 256, 0, stream>>>(x, avg, w1, b1, fscale, conv_bias, out);
}